// Round 4
// baseline (529.660 us; speedup 1.0000x reference)
//
#include <hip/hip_runtime.h>
#include <hip/hip_bf16.h>

// Problem constants (match reference)
#define NB   8
#define NN   256
#define NM   32
#define NHW  32768

// Decomposition: grid = NT4(4 n-tiles of 64) x CCH(16 c-chunks) x NB(8) = 512 blocks
// block = 512 threads = 8 waves; wave owns CW = 256 consecutive c (8 K-steps of 32).
#define NT4    4
#define CCH    16
#define CSLAB  (NHW / CCH)     // 2048 c per chunk
#define WPB    8
#define CW     (CSLAB / WPB)   // 256 c per wave
#define KSTEPS (CW / 32)       // 8

// ws layout (floats) -- every cell written exactly once, no memset needed
#define OFF_DXP  0                           // [CCH][NB][NT4][64n*32m]
#define SZ_DXP   (CCH*NB*NT4*2048)
#define OFF_DSP  (OFF_DXP + SZ_DXP)
#define OFF_SNP  (OFF_DSP + SZ_DXP)          // [CCH][NB][256 n]
#define SZ_SNP   (CCH*NB*NN)
#define OFF_SSP  (OFF_SNP + SZ_SNP)
#define OFF_STGT (OFF_SSP + SZ_SNP)          // [CCH][NB][32 m]

typedef _Float16 half8 __attribute__((ext_vector_type(8)));
typedef float    f32x4 __attribute__((ext_vector_type(4)));

#define MFMA16(a, b, c) __builtin_amdgcn_mfma_f32_16x16x32_f16(a, b, c, 0, 0, 0)

// ---------------------------------------------------------------------------
// Fragment-direct MFMA contraction over c, 64n x 32m per block.
//   Dx[n,m] = sum_c x*t        Ds[n,m] = sum_c sigmoid(x)*t
//   Sn[n]   = sum_c (x + softplus(-x))   Ss[n] = sum_c sigmoid(x)
//   St[m]   = sum_c t   (computed from the already-loaded B data, nt4==0 only)
// A-frag (16x16x32 f16): lane holds A[row=lane&15][k=(lane>>4)*8+j]
// B-frag:                lane holds B[col=lane&15][k=(lane>>4)*8+j]
// D:                     lane reg r -> row=(lane>>4)*4+r, col=lane&15
__global__ __launch_bounds__(512, 4) void cost_main(
    const float* __restrict__ X,   // [NB][NHW][NN]
    const float* __restrict__ T,   // [NB][NM][NHW]
    float* __restrict__ ws) {
    const int blk = blockIdx.x;
    const int b   = blk & 7;                  // XCD-constant per b
    const int rr  = blk >> 3;
    const int ch  = rr & (CCH - 1);
    const int nt4 = rr >> 4;

    const int tid  = threadIdx.x;
    const int wave = tid >> 6;
    const int lane = tid & 63;
    const int l16  = lane & 15;
    const int quad = lane >> 4;

    const int n0 = nt4 * 64;
    const int c0 = ch * CSLAB + wave * CW;

    const float* Xp  = X + ((size_t)b * NHW + c0 + quad * 8) * NN + n0 + l16;
    const float* T0p = T + ((size_t)b * NM + l16) * NHW + c0 + quad * 8;
    const float* T1p = T0p + (size_t)16 * NHW;

    f32x4 ax0[4], ax1[4], as0[4], as1[4];
#pragma unroll
    for (int f = 0; f < 4; ++f) {
        ax0[f] = f32x4{0.f, 0.f, 0.f, 0.f};
        ax1[f] = f32x4{0.f, 0.f, 0.f, 0.f};
        as0[f] = f32x4{0.f, 0.f, 0.f, 0.f};
        as1[f] = f32x4{0.f, 0.f, 0.f, 0.f};
    }
    float sneg[4] = {0.f, 0.f, 0.f, 0.f};
    float ssig[4] = {0.f, 0.f, 0.f, 0.f};
    float ts0 = 0.f, ts1 = 0.f;

    for (int ks = 0; ks < KSTEPS; ++ks) {
        float4 ta = *(const float4*)(T0p);
        float4 tb = *(const float4*)(T0p + 4);
        float4 tc = *(const float4*)(T1p);
        float4 td = *(const float4*)(T1p + 4);
        half8 ht0 = {(_Float16)ta.x, (_Float16)ta.y, (_Float16)ta.z, (_Float16)ta.w,
                     (_Float16)tb.x, (_Float16)tb.y, (_Float16)tb.z, (_Float16)tb.w};
        half8 ht1 = {(_Float16)tc.x, (_Float16)tc.y, (_Float16)tc.z, (_Float16)tc.w,
                     (_Float16)td.x, (_Float16)td.y, (_Float16)td.z, (_Float16)td.w};
        ts0 += (ta.x + ta.y) + (ta.z + ta.w) + (tb.x + tb.y) + (tb.z + tb.w);
        ts1 += (tc.x + tc.y) + (tc.z + tc.w) + (td.x + td.y) + (td.z + td.w);

#pragma unroll
        for (int f = 0; f < 4; ++f) {
            float xv[8];
#pragma unroll
            for (int j = 0; j < 8; ++j)
                xv[j] = Xp[(size_t)j * NN + f * 16];   // 256B contiguous per c-row
            half8 hx, hs;
#pragma unroll
            for (int j = 0; j < 8; ++j) {
                float x = xv[j];
                float e = __expf(-fabsf(x));                    // exp(-|x|) <= 1
                float rc = __builtin_amdgcn_rcpf(1.f + e);
                float s  = (x >= 0.f) ? rc : 1.f - rc;          // stable sigmoid
                float pos = fmaxf(-x, 0.f) + __logf(1.f + e);   // softplus(-x)
                sneg[f] += x + pos;
                ssig[f] += s;
                hx[j] = (_Float16)x;
                hs[j] = (_Float16)s;
            }
            ax0[f] = MFMA16(hx, ht0, ax0[f]);
            ax1[f] = MFMA16(hx, ht1, ax1[f]);
            as0[f] = MFMA16(hs, ht0, as0[f]);
            as1[f] = MFMA16(hs, ht1, as1[f]);
        }
        Xp  += (size_t)32 * NN;
        T0p += 32;
        T1p += 32;
    }

    // ---- in-block reduction across 8 waves ----
    __shared__ float redx[2048];    // [64 n][32 m]
    __shared__ float reds[2048];
    __shared__ float redn[64];
    __shared__ float redss[64];
    __shared__ float redt[32];
    for (int i = tid; i < 2048; i += 512) { redx[i] = 0.f; reds[i] = 0.f; }
    if (tid < 64) { redn[tid] = 0.f; redss[tid] = 0.f; }
    if (tid < 32) redt[tid] = 0.f;
    __syncthreads();

#pragma unroll
    for (int f = 0; f < 4; ++f) {
#pragma unroll
        for (int r = 0; r < 4; ++r) {
            const int row = f * 16 + quad * 4 + r;
            atomicAdd(&redx[row * 32 + l16],      ax0[f][r]);
            atomicAdd(&redx[row * 32 + l16 + 16], ax1[f][r]);
            atomicAdd(&reds[row * 32 + l16],      as0[f][r]);
            atomicAdd(&reds[row * 32 + l16 + 16], as1[f][r]);
        }
        // reduce across quads (lanes with equal l16 hold same n, different c)
        float sn = sneg[f], ss = ssig[f];
        sn += __shfl_xor(sn, 16); sn += __shfl_xor(sn, 32);
        ss += __shfl_xor(ss, 16); ss += __shfl_xor(ss, 32);
        if (lane < 16) {
            atomicAdd(&redn[f * 16 + l16], sn);
            atomicAdd(&redss[f * 16 + l16], ss);
        }
    }
    {
        float t0 = ts0, t1 = ts1;
        t0 += __shfl_xor(t0, 16); t0 += __shfl_xor(t0, 32);
        t1 += __shfl_xor(t1, 16); t1 += __shfl_xor(t1, 32);
        if (lane < 16) {
            atomicAdd(&redt[l16], t0);
            atomicAdd(&redt[l16 + 16], t1);
        }
    }
    __syncthreads();

    // ---- store per-chunk partials (plain coalesced stores) ----
    const size_t base = (((size_t)ch * NB + b) * NT4 + nt4) * 2048;
    for (int i = tid; i < 2048; i += 512) {
        ws[OFF_DXP + base + i] = redx[i];
        ws[OFF_DSP + base + i] = reds[i];
    }
    if (tid < 64) {
        const size_t sb = ((size_t)ch * NB + b) * NN + n0 + tid;
        ws[OFF_SNP + sb] = redn[tid];
        ws[OFF_SSP + sb] = redss[tid];
    }
    if (nt4 == 0 && tid < 32)
        ws[OFF_STGT + ((size_t)ch * NB + b) * NM + tid] = redt[tid];
}

// ---------------------------------------------------------------------------
// Combine 16 chunk partials + class/center/dice formula.
__global__ __launch_bounds__(256) void cost_finalize(
    const float* __restrict__ P,    // [NB][NN][1]
    const float* __restrict__ CD,   // [NB][NN][NM]
    const int*   __restrict__ LAB,  // [NB][NM]
    const float* __restrict__ ws,
    float* __restrict__ out) {
    const int idx = blockIdx.x * 256 + threadIdx.x;   // (b*NN+n)*NM+m
    const int m = idx & 31;
    const int n = (idx >> 5) & 255;
    const int b = idx >> 13;
    const int nt4 = n >> 6, nl = n & 63;

    float dx = 0.f, ds = 0.f, sn = 0.f, ss = 0.f, st = 0.f;
#pragma unroll
    for (int ch = 0; ch < CCH; ++ch) {
        const size_t base = (((size_t)ch * NB + b) * NT4 + nt4) * 2048 + nl * 32 + m;
        dx += ws[OFF_DXP + base];
        ds += ws[OFF_DSP + base];
        sn += ws[OFF_SNP + ((size_t)ch * NB + b) * NN + n];
        ss += ws[OFF_SSP + ((size_t)ch * NB + b) * NN + n];
        st += ws[OFF_STGT + ((size_t)ch * NB + b) * NM + m];
    }
    const float p   = P[b * NN + n];
    const int   lab = LAB[b * NM + m];
    const float cls = lab ? -p : (p - 1.f);

    const float cmask = (sn - dx) * (1.f / (float)NHW);
    const float dice  = 1.f - (2.f * ds + 1.f) / (ss + st + 1.f);

    out[idx] = 2.f * cls + CD[idx] + 5.f * cmask + 2.f * dice;
}

// ---------------------------------------------------------------------------
extern "C" void kernel_launch(void* const* d_in, const int* in_sizes, int n_in,
                              void* d_out, int out_size, void* d_ws, size_t ws_size,
                              hipStream_t stream) {
    const float* P   = (const float*)d_in[0];  // sem_cls_prob
    const float* CD  = (const float*)d_in[1];  // center_dist
    const float* X   = (const float*)d_in[2];  // mask_heatmaps
    const float* T   = (const float*)d_in[3];  // mask_tgt
    const int*   LAB = (const int*)d_in[4];    // gt_plane_sem_cls_label
    float* out = (float*)d_out;
    float* ws  = (float*)d_ws;

    hipLaunchKernelGGL(cost_main, dim3(NT4 * CCH * NB), dim3(512), 0, stream, X, T, ws);
    hipLaunchKernelGGL(cost_finalize, dim3((NB * NN * NM) / 256), dim3(256), 0, stream,
                       P, CD, LAB, ws, out);
}

// Round 5
// 420.359 us; speedup vs baseline: 1.2600x; 1.2600x over previous
//
#include <hip/hip_runtime.h>
#include <hip/hip_bf16.h>

// Problem constants (match reference)
#define NB   8
#define NN   256
#define NM   32
#define NHW  32768

// Grid: NB(8) x CCH(64) = 512 blocks (2/CU), 512 threads = 8 waves.
// Block owns ALL n=256 and a c-slab of 512; kstep = 32 c, double-buffered LDS.
// Wave w owns n in [32w, 32w+32) exclusively -> no cross-wave reduction.
#define CCH    64
#define CSLAB  (NHW / CCH)     // 512 c per block
#define KC     32              // c per kstep
#define KSTEPS (CSLAB / KC)    // 16

// ws layout (floats) -- every cell written exactly once, no memset needed
#define OFF_DXP  0                           // [CCH][NB][NN][NM]
#define SZ_DXP   (CCH*NB*NN*NM)
#define OFF_DSP  (OFF_DXP + SZ_DXP)
#define OFF_SNP  (OFF_DSP + SZ_DXP)          // [CCH][NB][NN]
#define SZ_SNP   (CCH*NB*NN)
#define OFF_SSP  (OFF_SNP + SZ_SNP)
#define OFF_STGT (OFF_SSP + SZ_SNP)          // [CCH][NB][NM]

typedef _Float16 half8 __attribute__((ext_vector_type(8)));
typedef float    f32x4 __attribute__((ext_vector_type(4)));

#define MFMA16(a, b, c) __builtin_amdgcn_mfma_f32_16x16x32_f16(a, b, c, 0, 0, 0)

typedef const __attribute__((address_space(1))) unsigned int* gp_t;
typedef __attribute__((address_space(3))) unsigned int*       lp_t;

// Stage one 1KB X row (256 f32) into LDS: lane's 16B from gsrc+lane*16 lands at
// ldst+lane*16 (wave-uniform LDS base + lane*size).
__device__ __forceinline__ void stage_row(const float* gsrc, float* ldst, int lane) {
#if __has_builtin(__builtin_amdgcn_global_load_lds)
    __builtin_amdgcn_global_load_lds((gp_t)(const void*)(gsrc + lane * 4),
                                     (lp_t)(void*)ldst, 16, 0, 0);
#else
    float4 v = *(const float4*)(gsrc + lane * 4);
    *(float4*)(ldst + lane * 4) = v;
#endif
}

// ---------------------------------------------------------------------------
// Fragment-direct MFMA contraction, 256n x 32m per block, LDS-staged X.
//   Dx[n,m] = sum_c x*t        Ds[n,m] = sum_c sigmoid(x)*t
//   Sn[n]   = sum_c (x + softplus(-x))   Ss[n] = sum_c sigmoid(x)
//   St[m]   = sum_c t
// A-frag (16x16x32 f16): lane holds A[row=lane&15][k=(lane>>4)*8+j]
// B-frag:                lane holds B[col=lane&15][k=(lane>>4)*8+j]
// D:                     lane reg r -> row=(lane>>4)*4+r, col=lane&15
__global__ __launch_bounds__(512, 4) void cost_main(
    const float* __restrict__ X,   // [NB][NHW][NN]
    const float* __restrict__ T,   // [NB][NM][NHW]
    float* __restrict__ ws) {
    const int blk = blockIdx.x;
    const int b   = blk & 7;                  // XCD-constant per b
    const int ch  = blk >> 3;                 // 0..63

    const int tid  = threadIdx.x;
    const int wave = tid >> 6;
    const int lane = tid & 63;
    const int l16  = lane & 15;
    const int quad = lane >> 4;

    const int c0 = ch * CSLAB;

    __shared__ __align__(16) float xs[2][KC][NN];   // 2 x 32 KB

    const float* Xbase = X + ((size_t)b * NHW + c0) * NN;   // row r = c0+r
    const float* Tp0   = T + ((size_t)b * NM + l16) * NHW + c0 + quad * 8;
    const float* Tp1   = Tp0 + (size_t)16 * NHW;

    // Prologue: stage slab 0 (wave w stages rows w, w+8, w+16, w+24)
#pragma unroll
    for (int r = 0; r < 4; ++r) {
        const int row = wave + r * 8;
        stage_row(Xbase + (size_t)row * NN, &xs[0][row][0], lane);
    }

    f32x4 ax0[2], ax1[2], as0[2], as1[2];
#pragma unroll
    for (int f = 0; f < 2; ++f) {
        ax0[f] = f32x4{0.f, 0.f, 0.f, 0.f};
        ax1[f] = f32x4{0.f, 0.f, 0.f, 0.f};
        as0[f] = f32x4{0.f, 0.f, 0.f, 0.f};
        as1[f] = f32x4{0.f, 0.f, 0.f, 0.f};
    }
    float sneg[2] = {0.f, 0.f};
    float ssig[2] = {0.f, 0.f};
    float ts0 = 0.f, ts1 = 0.f;

    for (int ks = 0; ks < KSTEPS; ++ks) {
        __syncthreads();                       // xs[ks&1] staged (drains vmcnt)
        const int nb = ks + 1;
        if (nb < KSTEPS) {                     // stage next slab while computing
            const float* Xn = Xbase + (size_t)nb * KC * NN;
#pragma unroll
            for (int r = 0; r < 4; ++r) {
                const int row = wave + r * 8;
                stage_row(Xn + (size_t)row * NN, &xs[nb & 1][row][0], lane);
            }
        }

        // B fragments: direct global float4 (same lines for all 8 waves -> L1/L2)
        float4 ta = *(const float4*)(Tp0 + ks * KC);
        float4 tb = *(const float4*)(Tp0 + ks * KC + 4);
        float4 tc = *(const float4*)(Tp1 + ks * KC);
        float4 td = *(const float4*)(Tp1 + ks * KC + 4);
        half8 ht0 = {(_Float16)ta.x, (_Float16)ta.y, (_Float16)ta.z, (_Float16)ta.w,
                     (_Float16)tb.x, (_Float16)tb.y, (_Float16)tb.z, (_Float16)tb.w};
        half8 ht1 = {(_Float16)tc.x, (_Float16)tc.y, (_Float16)tc.z, (_Float16)tc.w,
                     (_Float16)td.x, (_Float16)td.y, (_Float16)td.z, (_Float16)td.w};
        ts0 += (ta.x + ta.y) + (ta.z + ta.w) + (tb.x + tb.y) + (tb.z + tb.w);
        ts1 += (tc.x + tc.y) + (tc.z + tc.w) + (td.x + td.y) + (td.z + td.w);

#pragma unroll
        for (int f = 0; f < 2; ++f) {
            const int n = wave * 32 + f * 16 + l16;
            float xv[8];
#pragma unroll
            for (int j = 0; j < 8; ++j)
                xv[j] = xs[ks & 1][quad * 8 + j][n];
            half8 hx, hs;
#pragma unroll
            for (int j = 0; j < 8; ++j) {
                float x = xv[j];
                float e = __expf(-fabsf(x));                    // exp(-|x|) <= 1
                float rc = __builtin_amdgcn_rcpf(1.f + e);
                float s  = (x >= 0.f) ? rc : 1.f - rc;          // stable sigmoid
                float pos = fmaxf(-x, 0.f) + __logf(1.f + e);   // softplus(-x)
                sneg[f] += x + pos;
                ssig[f] += s;
                hx[j] = (_Float16)x;
                hs[j] = (_Float16)s;
            }
            ax0[f] = MFMA16(hx, ht0, ax0[f]);
            ax1[f] = MFMA16(hx, ht1, ax1[f]);
            as0[f] = MFMA16(hs, ht0, as0[f]);
            as1[f] = MFMA16(hs, ht1, as1[f]);
        }
    }

    // ---- epilogue: wave-exclusive n-stripes -> plain stores, no reduction ----
#pragma unroll
    for (int f = 0; f < 2; ++f) {
        float sn = sneg[f], ss = ssig[f];     // 4 quads share n -> quad-reduce
        sn += __shfl_xor(sn, 16); sn += __shfl_xor(sn, 32);
        ss += __shfl_xor(ss, 16); ss += __shfl_xor(ss, 32);
        if (lane < 16) {
            const size_t sb = ((size_t)ch * NB + b) * NN + wave * 32 + f * 16 + l16;
            ws[OFF_SNP + sb] = sn;
            ws[OFF_SSP + sb] = ss;
        }
    }
    if (wave == 0) {                           // all waves computed identical ts
        float t0 = ts0, t1 = ts1;
        t0 += __shfl_xor(t0, 16); t0 += __shfl_xor(t0, 32);
        t1 += __shfl_xor(t1, 16); t1 += __shfl_xor(t1, 32);
        if (lane < 16) {
            const size_t tb_ = ((size_t)ch * NB + b) * NM;
            ws[OFF_STGT + tb_ + l16]      = t0;
            ws[OFF_STGT + tb_ + l16 + 16] = t1;
        }
    }
    const size_t dbase = ((size_t)ch * NB + b) * NN * NM;
#pragma unroll
    for (int f = 0; f < 2; ++f) {
#pragma unroll
        for (int r = 0; r < 4; ++r) {
            const int n = wave * 32 + f * 16 + quad * 4 + r;
            const size_t o = dbase + (size_t)n * NM;
            ws[OFF_DXP + o + l16]      = ax0[f][r];
            ws[OFF_DXP + o + l16 + 16] = ax1[f][r];
            ws[OFF_DSP + o + l16]      = as0[f][r];
            ws[OFF_DSP + o + l16 + 16] = as1[f][r];
        }
    }
}

// ---------------------------------------------------------------------------
// Combine 64 chunk partials + class/center/dice formula.
__global__ __launch_bounds__(256) void cost_finalize(
    const float* __restrict__ P,    // [NB][NN][1]
    const float* __restrict__ CD,   // [NB][NN][NM]
    const int*   __restrict__ LAB,  // [NB][NM]
    const float* __restrict__ ws,
    float* __restrict__ out) {
    const int idx = blockIdx.x * 256 + threadIdx.x;   // (b*NN+n)*NM+m
    const int m = idx & 31;
    const int n = (idx >> 5) & 255;
    const int b = idx >> 13;

    float dx = 0.f, ds = 0.f, sn = 0.f, ss = 0.f, st = 0.f;
    for (int ch = 0; ch < CCH; ++ch) {
        const size_t e = (size_t)ch * NB + b;
        dx += ws[OFF_DXP + (e * NN + n) * NM + m];
        ds += ws[OFF_DSP + (e * NN + n) * NM + m];
        sn += ws[OFF_SNP + e * NN + n];
        ss += ws[OFF_SSP + e * NN + n];
        st += ws[OFF_STGT + e * NM + m];
    }
    const float p   = P[b * NN + n];
    const int   lab = LAB[b * NM + m];
    const float cls = lab ? -p : (p - 1.f);

    const float cmask = (sn - dx) * (1.f / (float)NHW);
    const float dice  = 1.f - (2.f * ds + 1.f) / (ss + st + 1.f);

    out[idx] = 2.f * cls + CD[idx] + 5.f * cmask + 2.f * dice;
}

// ---------------------------------------------------------------------------
extern "C" void kernel_launch(void* const* d_in, const int* in_sizes, int n_in,
                              void* d_out, int out_size, void* d_ws, size_t ws_size,
                              hipStream_t stream) {
    const float* P   = (const float*)d_in[0];  // sem_cls_prob
    const float* CD  = (const float*)d_in[1];  // center_dist
    const float* X   = (const float*)d_in[2];  // mask_heatmaps
    const float* T   = (const float*)d_in[3];  // mask_tgt
    const int*   LAB = (const int*)d_in[4];    // gt_plane_sem_cls_label
    float* out = (float*)d_out;
    float* ws  = (float*)d_ws;

    hipLaunchKernelGGL(cost_main, dim3(NB * CCH), dim3(512), 0, stream, X, T, ws);
    hipLaunchKernelGGL(cost_finalize, dim3((NB * NN * NM) / 256), dim3(256), 0, stream,
                       P, CD, LAB, ws, out);
}